// Round 8
// baseline (1102.148 us; speedup 1.0000x reference)
//
#include <hip/hip_runtime.h>
#include <math.h>

#define NKER 125

// ---------------- hist: count edges per dst ----------------
__global__ __launch_bounds__(256) void hist_kernel(const int* __restrict__ ei,
                                                   int* __restrict__ hist, int E) {
  int e = blockIdx.x * 256 + threadIdx.x;
  if (e < E) atomicAdd(&hist[ei[E + e]], 1);
}

// ---------------- scan6: per-layer exclusive prefix over hist -> start, cursor ----------------
__global__ __launch_bounds__(1024) void scan6_kernel(int* __restrict__ hist,
                                                     int* __restrict__ start,
                                                     int* __restrict__ cursor) {
  static const int histOff[6] = {0, 20000, 25000, 26280, 26600, 26680};
  static const int startOff[6] = {0, 20001, 25002, 26283, 26604, 26685};
  static const int Nl[6] = {20000, 5000, 1280, 320, 80, 32};
  __shared__ int ps[1024];
  int b = blockIdx.x;
  int* h = hist + histOff[b];
  int* s = start + startOff[b];
  int* c = cursor + histOff[b];
  int N = Nl[b];
  int t = threadIdx.x;
  int chunk = (N + 1023) / 1024;
  int lo = min(N, t * chunk), hi = min(N, lo + chunk);
  int sum = 0;
  for (int i = lo; i < hi; i++) sum += h[i];
  ps[t] = sum;
  __syncthreads();
  for (int off = 1; off < 1024; off <<= 1) {
    int v = (t >= off) ? ps[t - off] : 0;
    __syncthreads();
    ps[t] += v;
    __syncthreads();
  }
  int base = (t == 0) ? 0 : ps[t - 1];
  for (int i = lo; i < hi; i++) {
    int hv = h[i];
    s[i] = base;
    c[i] = base;
    base += hv;
  }
  if (t == 1023) s[N] = ps[1023];
}

// ---------------- reorder: place edge data at sorted-by-dst positions ----------------
__global__ __launch_bounds__(256) void reorder_kernel(
    const int* __restrict__ ei, const float* __restrict__ ea,
    int* __restrict__ cursor, int* __restrict__ srcS, int* __restrict__ kpkS,
    float* __restrict__ frS, int E) {
  int e = blockIdx.x * 256 + threadIdx.x;
  if (e >= E) return;
  int src = ei[e];
  int dst = ei[E + e];
  int kpk = 0;
  float f[3];
#pragma unroll
  for (int d = 0; d < 3; d++) {
    float p = ea[e * 3 + d] * 4.0f;
    float kf = fminf(fmaxf(floorf(p), 0.0f), 3.0f);
    f[d] = p - kf;
    kpk |= ((int)kf) << (4 * d);
  }
  int pos = atomicAdd(&cursor[dst], 1);
  srcS[pos] = src;
  kpkS[pos] = kpk;
  frS[pos * 3 + 0] = f[0];
  frS[pos * 3 + 1] = f[1];
  frS[pos * 3 + 2] = f[2];
}

// ---------------- build: per-block NB nodes; accumulate A-rows in LDS; vector write-out ----------------
template <int CINSH, int NB, int KS>
__global__ __launch_bounds__(256) void build_kernel(
    const int* __restrict__ start, const int* __restrict__ srcS,
    const int* __restrict__ kpkS, const float* __restrict__ frS,
    const float* __restrict__ x, float* __restrict__ A) {
  __shared__ float rows[NB * KS];
  __shared__ int sst[NB + 1];
  const int Cin = 1 << CINSH;
  int n0 = blockIdx.x * NB;
  if (threadIdx.x <= NB) sst[threadIdx.x] = start[n0 + threadIdx.x];
  for (int t = threadIdx.x; t < NB * KS / 4; t += 256)
    ((float4*)rows)[t] = make_float4(0.0f, 0.0f, 0.0f, 0.0f);
  __syncthreads();
  int e0 = sst[0], e1 = sst[NB];
  int tot = (e1 - e0) << (3 + CINSH);
  for (int it = threadIdx.x; it < tot; it += 256) {
    int ci = it & (Cin - 1);
    int corner = (it >> CINSH) & 7;
    int e = e0 + (it >> (3 + CINSH));
    int nl;
    if (NB == 1) {
      nl = 0;
    } else {
      int lo = 0, hi = NB;
      while (hi - lo > 1) {
        int mid = (lo + hi) >> 1;
        if (e >= sst[mid]) lo = mid; else hi = mid;
      }
      nl = lo;
    }
    int kpk = kpkS[e];
    float f0 = frS[3 * e], f1 = frS[3 * e + 1], f2 = frS[3 * e + 2];
    int b0 = corner & 1, b1 = (corner >> 1) & 1, b2 = corner >> 2;
    float w = (b0 ? f0 : 1.0f - f0) * (b1 ? f1 : 1.0f - f1) * (b2 ? f2 : 1.0f - f2);
    int kidx = ((kpk & 15) + b0) + 5 * (((kpk >> 4) & 15) + b1) + 25 * (((kpk >> 8) & 15) + b2);
    float xv = x[((size_t)srcS[e] << CINSH) + ci];
    atomicAdd(&rows[nl * KS + (kidx << CINSH) + ci], w * xv);
  }
  __syncthreads();
  float4* dst4 = (float4*)&A[(size_t)n0 * KS];
  for (int t = threadIdx.x; t < NB * KS / 4; t += 256) dst4[t] = ((float4*)rows)[t];
}

// ---------------- GEMM v3: register-tiled 4x4, float4 staging, partials out ----------------
template <int BM, int COUT, int NT>
__global__ __launch_bounds__(NT) void gemm3_kernel(
    const float* __restrict__ A, const float* __restrict__ W,
    float* __restrict__ gpart, int M, int Kdim, int KS, int ktiles) {
  const int BK = 32;
  __shared__ float At[BK][BM + 4];
  __shared__ float Wl[BK][COUT];
  const int TC = COUT / 4;
  int tid = threadIdx.x;
  int tc = tid % TC;
  int tr = tid / TC;
  int m0 = blockIdx.x * BM;
  int kbeg = blockIdx.y * ktiles * BK;
  int kend = min(KS, kbeg + ktiles * BK);
  float ar[4][4];
#pragma unroll
  for (int i = 0; i < 4; i++)
#pragma unroll
    for (int j = 0; j < 4; j++) ar[i][j] = 0.0f;

  for (int k0 = kbeg; k0 < kend; k0 += BK) {
    for (int t = tid; t < BM * (BK / 4); t += NT) {
      int c4 = t % (BK / 4), r = t / (BK / 4);
      int m = m0 + r;
      float4 v = make_float4(0.0f, 0.0f, 0.0f, 0.0f);
      if (m < M) v = *(const float4*)&A[(size_t)m * KS + k0 + c4 * 4];
      At[c4 * 4 + 0][r] = v.x; At[c4 * 4 + 1][r] = v.y;
      At[c4 * 4 + 2][r] = v.z; At[c4 * 4 + 3][r] = v.w;
    }
    int kleft = Kdim - k0;
    if (kleft >= BK) {
      for (int t = tid; t < BK * COUT / 4; t += NT)
        ((float4*)&Wl[0][0])[t] = ((const float4*)&W[(size_t)k0 * COUT])[t];
    } else {
      for (int t = tid; t < BK * COUT; t += NT) {
        int kk = t / COUT, o = t % COUT;
        Wl[kk][o] = (kk < kleft) ? W[(size_t)(k0 + kk) * COUT + o] : 0.0f;
      }
    }
    __syncthreads();
#pragma unroll
    for (int kk = 0; kk < BK; kk++) {
      float4 a = *(const float4*)&At[kk][tr * 4];
      float4 w = *(const float4*)&Wl[kk][tc * 4];
      float av[4] = {a.x, a.y, a.z, a.w};
      float wv[4] = {w.x, w.y, w.z, w.w};
#pragma unroll
      for (int i = 0; i < 4; i++)
#pragma unroll
        for (int j = 0; j < 4; j++)
          ar[i][j] = fmaf(av[i], wv[j], ar[i][j]);
    }
    __syncthreads();
  }
  float* gp = gpart + ((size_t)blockIdx.y * M) * COUT + tc * 4;
#pragma unroll
  for (int i = 0; i < 4; i++) {
    int m = m0 + tr * 4 + i;
    if (m < M)
      *(float4*)(gp + (size_t)m * COUT) =
          make_float4(ar[i][0], ar[i][1], ar[i][2], ar[i][3]);
  }
}

// ---------------- epilogue: h = elu(sum_c gpart[c]/max(deg,1) + x@R + b); deg = hist ----------------
__global__ __launch_bounds__(256) void epilogue_kernel(
    const float* __restrict__ gpart, const int* __restrict__ degI,
    const float* __restrict__ x, const float* __restrict__ R,
    const float* __restrict__ b, float* __restrict__ h,
    int N, int Cin, int coutShift, int kchunks) {
  int tid = blockIdx.x * 256 + threadIdx.x;
  int Cout = 1 << coutShift;
  if (tid >= (N << coutShift)) return;
  int n = tid >> coutShift;
  int o = tid & (Cout - 1);
  size_t stride = (size_t)N << coutShift;
  float s = 0.0f;
  for (int c = 0; c < kchunks; c++) s += gpart[(size_t)c * stride + tid];
  s /= (float)max(degI[n], 1);
  float r = b[o];
  const float* xr = &x[n * Cin];
  for (int i = 0; i < Cin; i++) r = fmaf(xr[i], R[i * Cout + o], r);
  float v = s + r;
  h[tid] = v > 0.0f ? v : expm1f(v);
}

// ---------------- pool v5b: named-float4 accumulators, h tile in LDS ----------------
#define FMA4(c, pj, h) \
  c.x = fmaf(pj, h.x, c.x); c.y = fmaf(pj, h.y, c.y); \
  c.z = fmaf(pj, h.z, c.z); c.w = fmaf(pj, h.w, c.w);

template <int COUT, int OPT>
__global__ __launch_bounds__(256) void pool5b_kernel(
    const float* __restrict__ P, const float* __restrict__ h,
    float* __restrict__ partial, int Nsrc, int Nnext, int chunk, int items) {
  extern __shared__ float hs[];
  int c = blockIdx.y;
  int n0 = c * chunk;
  int n1 = min(Nsrc, n0 + chunk);
  int len = n1 - n0;
  for (int t = threadIdx.x; t < len * (COUT / 4); t += 256)
    ((float4*)hs)[t] = ((const float4*)&h[(size_t)n0 * COUT])[t];
  __syncthreads();
  int item = blockIdx.x * 256 + threadIdx.x;
  if (item >= items) return;
  int nj4 = Nnext >> 2;
  int j0 = (item % nj4) << 2;
  int o0 = (item / nj4) * OPT;
  const float4 z = make_float4(0.0f, 0.0f, 0.0f, 0.0f);
  float4 c00 = z, c01 = z, c02 = z, c03 = z;
  float4 c10 = z, c11 = z, c12 = z, c13 = z;
  float4 c20 = z, c21 = z, c22 = z, c23 = z;
  float4 c30 = z, c31 = z, c32 = z, c33 = z;
  const float* Pb = P + j0;

#define USTEP(pv, nn)                                                    \
  {                                                                      \
    const float4* hr = (const float4*)&hs[(nn) * COUT + o0];             \
    float4 h0 = hr[0], h1 = hr[1];                                       \
    FMA4(c00, pv.x, h0) FMA4(c01, pv.x, h1)                              \
    FMA4(c10, pv.y, h0) FMA4(c11, pv.y, h1)                              \
    FMA4(c20, pv.z, h0) FMA4(c21, pv.z, h1)                              \
    FMA4(c30, pv.w, h0) FMA4(c31, pv.w, h1)                              \
    if constexpr (OPT == 16) {                                           \
      float4 h2 = hr[2], h3 = hr[3];                                     \
      FMA4(c02, pv.x, h2) FMA4(c03, pv.x, h3)                            \
      FMA4(c12, pv.y, h2) FMA4(c13, pv.y, h3)                            \
      FMA4(c22, pv.z, h2) FMA4(c23, pv.z, h3)                            \
      FMA4(c32, pv.w, h2) FMA4(c33, pv.w, h3)                            \
    }                                                                    \
  }

  int n = 0;
  for (; n + 4 <= len; n += 4) {
    float4 pv0 = *(const float4*)&Pb[(size_t)(n0 + n + 0) * Nnext];
    float4 pv1 = *(const float4*)&Pb[(size_t)(n0 + n + 1) * Nnext];
    float4 pv2 = *(const float4*)&Pb[(size_t)(n0 + n + 2) * Nnext];
    float4 pv3 = *(const float4*)&Pb[(size_t)(n0 + n + 3) * Nnext];
    USTEP(pv0, n + 0)
    USTEP(pv1, n + 1)
    USTEP(pv2, n + 2)
    USTEP(pv3, n + 3)
  }
  for (; n < len; n++) {
    float4 pv = *(const float4*)&Pb[(size_t)(n0 + n) * Nnext];
    USTEP(pv, n)
  }
#undef USTEP

  float* pp = partial + ((size_t)c * Nnext + j0) * COUT + o0;
  *(float4*)(pp + 0 * COUT + 0) = c00;
  *(float4*)(pp + 0 * COUT + 4) = c01;
  *(float4*)(pp + 1 * COUT + 0) = c10;
  *(float4*)(pp + 1 * COUT + 4) = c11;
  *(float4*)(pp + 2 * COUT + 0) = c20;
  *(float4*)(pp + 2 * COUT + 4) = c21;
  *(float4*)(pp + 3 * COUT + 0) = c30;
  *(float4*)(pp + 3 * COUT + 4) = c31;
  if constexpr (OPT == 16) {
    *(float4*)(pp + 0 * COUT + 8)  = c02;
    *(float4*)(pp + 0 * COUT + 12) = c03;
    *(float4*)(pp + 1 * COUT + 8)  = c12;
    *(float4*)(pp + 1 * COUT + 12) = c13;
    *(float4*)(pp + 2 * COUT + 8)  = c22;
    *(float4*)(pp + 2 * COUT + 12) = c23;
    *(float4*)(pp + 3 * COUT + 8)  = c32;
    *(float4*)(pp + 3 * COUT + 12) = c33;
  }
}

// ---------------- pool reduce ----------------
__global__ __launch_bounds__(256) void preduce_kernel(
    const float* __restrict__ partial, float* __restrict__ xnext,
    int NnCout, int chunks) {
  int i = blockIdx.x * 256 + threadIdx.x;
  if (i >= NnCout) return;
  float s = 0.0f;
  for (int c = 0; c < chunks; c++) s += partial[(size_t)c * NnCout + i];
  xnext[i] = s;
}

// ---------------- final max over 16 nodes -> out[128] ----------------
__global__ __launch_bounds__(128) void max_kernel(const float* __restrict__ x6,
                                                  float* __restrict__ out) {
  int o = threadIdx.x;
  float m = -3.0e38f;
  for (int n = 0; n < 16; n++) m = fmaxf(m, x6[n * 128 + o]);
  out[o] = m;
}

extern "C" void kernel_launch(void* const* d_in, const int* in_sizes, int n_in,
                              void* d_out, int out_size, void* d_ws, size_t ws_size,
                              hipStream_t stream) {
  static const int NSh[7] = {20000, 5000, 1280, 320, 80, 32, 16};
  static const int ESh[6] = {320000, 80000, 20480, 5120, 1280, 512};
  static const int NFh[7] = {2, 16, 32, 64, 128, 128, 128};
  static const int cinSh[6]  = {1, 4, 5, 6, 7, 7};
  static const int coutSh[6] = {4, 5, 6, 7, 7, 7};
  static const int KSt[6] = {256, 2016, 4000, 8000, 16000, 16000};
  static const int kchunksTab[6] = {4, 8, 16, 32, 64, 128};
  static const int ktilesTab[6]  = {2, 8, 8, 8, 8, 4};
  static const int poolChunksTab[6] = {120, 64, 16, 8, 4, 2};
  static const int histOff[6] = {0, 20000, 25000, 26280, 26600, 26680};
  static const int startOff[6] = {0, 20001, 25002, 26283, 26604, 26685};
  static const int Eoff[6] = {0, 320000, 400000, 420480, 425600, 426880};

  const float* x0 = (const float*)d_in[0];
  const int* ei[6];
  const float* ea[6];
  for (int l = 0; l < 6; l++) {
    ei[l] = (const int*)d_in[1 + 2 * l];
    ea[l] = (const float*)d_in[2 + 2 * l];
  }
  const float* Pm[6];
  for (int l = 0; l < 6; l++) Pm[l] = (const float*)d_in[13 + l];
  const float* Wt[6];
  const float* Rt[6];
  const float* bt[6];
  for (int l = 0; l < 6; l++) {
    Wt[l] = (const float*)d_in[19 + 3 * l];
    Rt[l] = (const float*)d_in[20 + 3 * l];
    bt[l] = (const float*)d_in[21 + 3 * l];
  }

  // workspace layout
  float* ws = (float*)d_ws;
  float* A     = ws;                  // max N*KS = 10.08M floats
  float* gpart = ws + 10150000;       // max 1.31M
  float* hbuf  = ws + 11500000;       // 320000
  float* ppart = ws + 11900000;       // max 9.6M
  float* xA    = ws + 21600000;
  float* xB    = ws + 21700000;
  int* hist    = (int*)(ws + 21800000);  // 26712
  int* startA  = (int*)(ws + 21830000);  // 26717
  int* cursor  = (int*)(ws + 21860000);  // 26712
  int* srcS    = (int*)(ws + 21890000);  // 427392
  int* kpkS    = (int*)(ws + 22320000);  // 427392
  float* frS   = ws + 22750000;          // 1282176

  // per-call edge sorting (deterministic work; FP order jitter << threshold)
  hipMemsetAsync(hist, 0, 26712 * sizeof(int), stream);
  for (int l = 0; l < 6; l++)
    hist_kernel<<<(ESh[l] + 255) / 256, 256, 0, stream>>>(ei[l], hist + histOff[l], ESh[l]);
  scan6_kernel<<<6, 1024, 0, stream>>>(hist, startA, cursor);
  for (int l = 0; l < 6; l++)
    reorder_kernel<<<(ESh[l] + 255) / 256, 256, 0, stream>>>(
        ei[l], ea[l], cursor + histOff[l], srcS + Eoff[l], kpkS + Eoff[l],
        frS + 3 * (size_t)Eoff[l], ESh[l]);

  const float* cur = x0;
  for (int l = 0; l < 6; l++) {
    int N = NSh[l], Nn = NSh[l + 1], Cin = NFh[l], Cout = NFh[l + 1];
    int Kdim = NKER * Cin, KS = KSt[l];
    float* xnext = (l & 1) ? xB : xA;
    const int* st = startA + startOff[l];
    const int* ss = srcS + Eoff[l];
    const int* kk = kpkS + Eoff[l];
    const float* ff = frS + 3 * (size_t)Eoff[l];

    switch (l) {
      case 0: build_kernel<1, 32, 256><<<625, 256, 0, stream>>>(st, ss, kk, ff, cur, A); break;
      case 1: build_kernel<4, 8, 2016><<<625, 256, 0, stream>>>(st, ss, kk, ff, cur, A); break;
      case 2: build_kernel<5, 4, 4000><<<320, 256, 0, stream>>>(st, ss, kk, ff, cur, A); break;
      case 3: build_kernel<6, 2, 8000><<<160, 256, 0, stream>>>(st, ss, kk, ff, cur, A); break;
      case 4: build_kernel<7, 1, 16000><<<80, 256, 0, stream>>>(st, ss, kk, ff, cur, A); break;
      default: build_kernel<7, 1, 16000><<<32, 256, 0, stream>>>(st, ss, kk, ff, cur, A); break;
    }

    int kchunks = kchunksTab[l], ktiles = ktilesTab[l];
    switch (l) {
      case 0: {
        dim3 g((N + 127) / 128, kchunks);
        gemm3_kernel<128, 16, 128><<<g, 128, 0, stream>>>(A, Wt[l], gpart, N, Kdim, KS, ktiles);
        break;
      }
      case 1: {
        dim3 g((N + 127) / 128, kchunks);
        gemm3_kernel<128, 32, 256><<<g, 256, 0, stream>>>(A, Wt[l], gpart, N, Kdim, KS, ktiles);
        break;
      }
      case 2: {
        dim3 g((N + 63) / 64, kchunks);
        gemm3_kernel<64, 64, 256><<<g, 256, 0, stream>>>(A, Wt[l], gpart, N, Kdim, KS, ktiles);
        break;
      }
      default: {
        dim3 g((N + 31) / 32, kchunks);
        gemm3_kernel<32, 128, 256><<<g, 256, 0, stream>>>(A, Wt[l], gpart, N, Kdim, KS, ktiles);
        break;
      }
    }

    int ethreads = N << coutSh[l];
    epilogue_kernel<<<(ethreads + 255) / 256, 256, 0, stream>>>(
        gpart, hist + histOff[l], cur, Rt[l], bt[l], hbuf, N, Cin, coutSh[l], kchunks);

    int pc = poolChunksTab[l];
    int chunk = (N + pc - 1) / pc;
    size_t ldsB = (size_t)chunk * Cout * sizeof(float);
    int items, gx;
    switch (Cout) {
      case 16:
        items = (Nn >> 2) * 1;
        gx = (items + 255) / 256;
        pool5b_kernel<16, 16><<<dim3(gx, pc), 256, ldsB, stream>>>(Pm[l], hbuf, ppart, N, Nn, chunk, items);
        break;
      case 32:
        items = (Nn >> 2) * 2;
        gx = (items + 255) / 256;
        pool5b_kernel<32, 16><<<dim3(gx, pc), 256, ldsB, stream>>>(Pm[l], hbuf, ppart, N, Nn, chunk, items);
        break;
      case 64:
        items = (Nn >> 2) * 8;
        gx = (items + 255) / 256;
        pool5b_kernel<64, 8><<<dim3(gx, pc), 256, ldsB, stream>>>(Pm[l], hbuf, ppart, N, Nn, chunk, items);
        break;
      default:
        items = (Nn >> 2) * 16;
        gx = (items + 255) / 256;
        pool5b_kernel<128, 8><<<dim3(gx, pc), 256, ldsB, stream>>>(Pm[l], hbuf, ppart, N, Nn, chunk, items);
        break;
    }
    int NnCout = Nn << coutSh[l];
    preduce_kernel<<<(NnCout + 255) / 256, 256, 0, stream>>>(ppart, xnext, NnCout, pc);

    cur = xnext;
  }

  max_kernel<<<1, 128, 0, stream>>>(cur, (float*)d_out);
}

// Round 11
// 819.934 us; speedup vs baseline: 1.3442x; 1.3442x over previous
//
#include <hip/hip_runtime.h>
#include <math.h>

#define NKER 125

// ---------------- hist: count edges per dst ----------------
__global__ __launch_bounds__(256) void hist_kernel(const int* __restrict__ ei,
                                                   int* __restrict__ hist, int E) {
  int e = blockIdx.x * 256 + threadIdx.x;
  if (e < E) atomicAdd(&hist[ei[E + e]], 1);
}

// ---------------- scan6: per-layer exclusive prefix over hist -> start, cursor ----------------
__global__ __launch_bounds__(1024) void scan6_kernel(int* __restrict__ hist,
                                                     int* __restrict__ start,
                                                     int* __restrict__ cursor) {
  static const int histOff[6] = {0, 20000, 25000, 26280, 26600, 26680};
  static const int startOff[6] = {0, 20001, 25002, 26283, 26604, 26685};
  static const int Nl[6] = {20000, 5000, 1280, 320, 80, 32};
  __shared__ int ps[1024];
  int b = blockIdx.x;
  int* h = hist + histOff[b];
  int* s = start + startOff[b];
  int* c = cursor + histOff[b];
  int N = Nl[b];
  int t = threadIdx.x;
  int chunk = (N + 1023) / 1024;
  int lo = min(N, t * chunk), hi = min(N, lo + chunk);
  int sum = 0;
  for (int i = lo; i < hi; i++) sum += h[i];
  ps[t] = sum;
  __syncthreads();
  for (int off = 1; off < 1024; off <<= 1) {
    int v = (t >= off) ? ps[t - off] : 0;
    __syncthreads();
    ps[t] += v;
    __syncthreads();
  }
  int base = (t == 0) ? 0 : ps[t - 1];
  for (int i = lo; i < hi; i++) {
    int hv = h[i];
    s[i] = base;
    c[i] = base;
    base += hv;
  }
  if (t == 1023) s[N] = ps[1023];
}

// ---------------- reorder: place edge data at sorted-by-dst positions ----------------
__global__ __launch_bounds__(256) void reorder_kernel(
    const int* __restrict__ ei, const float* __restrict__ ea,
    int* __restrict__ cursor, int* __restrict__ srcS, int* __restrict__ kpkS,
    float* __restrict__ frS, int E) {
  int e = blockIdx.x * 256 + threadIdx.x;
  if (e >= E) return;
  int src = ei[e];
  int dst = ei[E + e];
  int kpk = 0;
  float f[3];
#pragma unroll
  for (int d = 0; d < 3; d++) {
    float p = ea[e * 3 + d] * 4.0f;
    float kf = fminf(fmaxf(floorf(p), 0.0f), 3.0f);
    f[d] = p - kf;
    kpk |= ((int)kf) << (4 * d);
  }
  int pos = atomicAdd(&cursor[dst], 1);
  srcS[pos] = src;
  kpkS[pos] = kpk;
  frS[pos * 3 + 0] = f[0];
  frS[pos * 3 + 1] = f[1];
  frS[pos * 3 + 2] = f[2];
}

// ---------------- build2 generic: thread owns (node, ci); plain LDS RMW, no atomics ----------------
template <int CINSH, int G, int KDIM, int KSG, int NT>
__global__ __launch_bounds__(NT) void build2_kernel(
    const int* __restrict__ start, const int* __restrict__ srcS,
    const int* __restrict__ kpkS, const float* __restrict__ frS,
    const float* __restrict__ x, float* __restrict__ A) {
  __shared__ float rows[G * KDIM];
  const int Cin = 1 << CINSH;
  int tid = threadIdx.x;
  int n0 = blockIdx.x * G;
  for (int t = tid; t < G * KDIM / 4; t += NT)
    ((float4*)rows)[t] = make_float4(0.0f, 0.0f, 0.0f, 0.0f);
  __syncthreads();
  int nl = tid >> CINSH;
  int ci = tid & (Cin - 1);
  int n = n0 + nl;
  int e0 = start[n], e1 = start[n + 1];
  float* row = rows + nl * KDIM + ci;
  for (int e = e0; e < e1; e++) {
    int src = srcS[e];
    int kpk = kpkS[e];
    float f0 = frS[3 * e], f1 = frS[3 * e + 1], f2 = frS[3 * e + 2];
    float xv = x[((size_t)src << CINSH) + ci];
    float g0 = 1.0f - f0, g1 = 1.0f - f1, g2 = 1.0f - f2;
    int kb = (kpk & 15) + 5 * ((kpk >> 4) & 15) + 25 * ((kpk >> 8) & 15);
    float* rb = row + (kb << CINSH);
    rb[0]              += (g0 * g1 * g2) * xv;
    rb[1 << CINSH]     += (f0 * g1 * g2) * xv;
    rb[5 << CINSH]     += (g0 * f1 * g2) * xv;
    rb[6 << CINSH]     += (f0 * f1 * g2) * xv;
    rb[25 << CINSH]    += (g0 * g1 * f2) * xv;
    rb[26 << CINSH]    += (f0 * g1 * f2) * xv;
    rb[30 << CINSH]    += (g0 * f1 * f2) * xv;
    rb[31 << CINSH]    += (f0 * f1 * f2) * xv;
  }
  __syncthreads();
  // stream rows to global with zero pad (KDIM..KSG)
  const int RQ = KSG / 4;
  for (int t = tid; t < G * RQ; t += NT) {
    int r = t / RQ, c4 = t % RQ;
    int c = c4 * 4;
    float4 v = make_float4(0.0f, 0.0f, 0.0f, 0.0f);
    if (c < KDIM) v = *(const float4*)&rows[r * KDIM + c];
    ((float4*)&A[(size_t)(n0 + r) * KSG])[c4] = v;
  }
}

// ---------------- build2 L0: Cin=2, thread-per-node, float2 rows, stride 254 ----------------
__global__ __launch_bounds__(64) void build2_l0_kernel(
    const int* __restrict__ start, const int* __restrict__ srcS,
    const int* __restrict__ kpkS, const float* __restrict__ frS,
    const float* __restrict__ x, float* __restrict__ A, int N) {
  __shared__ float rows[64 * 254];  // 64 nodes x (250 data + pad), stride 254
  int tid = threadIdx.x;
  int n0 = blockIdx.x * 64;
  for (int t = tid; t < 64 * 254 / 4; t += 64)
    ((float4*)rows)[t] = make_float4(0.0f, 0.0f, 0.0f, 0.0f);
  __syncthreads();
  int n = n0 + tid;
  if (n < N) {
    int e0 = start[n], e1 = start[n + 1];
    float* row = rows + tid * 254;
    for (int e = e0; e < e1; e++) {
      int src = srcS[e];
      int kpk = kpkS[e];
      float f0 = frS[3 * e], f1 = frS[3 * e + 1], f2 = frS[3 * e + 2];
      float2 xv = *(const float2*)&x[(size_t)src * 2];
      float g0 = 1.0f - f0, g1 = 1.0f - f1, g2 = 1.0f - f2;
      int kb = (kpk & 15) + 5 * ((kpk >> 4) & 15) + 25 * ((kpk >> 8) & 15);
      float2* rb = (float2*)(row + kb * 2);
      float w;
#define CORNER(off, expr)                                         \
      {                                                           \
        w = (expr);                                               \
        float2 v = rb[off];                                       \
        v.x = fmaf(w, xv.x, v.x); v.y = fmaf(w, xv.y, v.y);       \
        rb[off] = v;                                              \
      }
      CORNER(0,  g0 * g1 * g2)
      CORNER(1,  f0 * g1 * g2)
      CORNER(5,  g0 * f1 * g2)
      CORNER(6,  f0 * f1 * g2)
      CORNER(25, g0 * g1 * f2)
      CORNER(26, f0 * g1 * f2)
      CORNER(30, g0 * f1 * f2)
      CORNER(31, f0 * f1 * f2)
#undef CORNER
    }
  }
  __syncthreads();
  // write out: iteration it handles node n0+it; lanes cover 64 float4 (256 floats, KSG=256)
  for (int it = 0; it < 64; it++) {
    int nn = n0 + it;
    if (nn >= N) break;
    int c = tid * 4;  // 0..252
    float4 v = make_float4(0.0f, 0.0f, 0.0f, 0.0f);
    if (tid < 63) v = *(const float4*)&rows[it * 254 + c];  // 250,251.. zero-filled at init
    ((float4*)&A[(size_t)nn * 256])[tid] = v;
  }
}

// ---------------- GEMM v3: register-tiled 4x4, float4 staging, partials out ----------------
template <int BM, int COUT, int NT>
__global__ __launch_bounds__(NT) void gemm3_kernel(
    const float* __restrict__ A, const float* __restrict__ W,
    float* __restrict__ gpart, int M, int Kdim, int KS, int ktiles) {
  const int BK = 32;
  __shared__ float At[BK][BM + 4];
  __shared__ float Wl[BK][COUT];
  const int TC = COUT / 4;
  int tid = threadIdx.x;
  int tc = tid % TC;
  int tr = tid / TC;
  int m0 = blockIdx.x * BM;
  int kbeg = blockIdx.y * ktiles * BK;
  int kend = min(KS, kbeg + ktiles * BK);
  float ar[4][4];
#pragma unroll
  for (int i = 0; i < 4; i++)
#pragma unroll
    for (int j = 0; j < 4; j++) ar[i][j] = 0.0f;

  for (int k0 = kbeg; k0 < kend; k0 += BK) {
    for (int t = tid; t < BM * (BK / 4); t += NT) {
      int c4 = t % (BK / 4), r = t / (BK / 4);
      int m = m0 + r;
      float4 v = make_float4(0.0f, 0.0f, 0.0f, 0.0f);
      if (m < M) v = *(const float4*)&A[(size_t)m * KS + k0 + c4 * 4];
      At[c4 * 4 + 0][r] = v.x; At[c4 * 4 + 1][r] = v.y;
      At[c4 * 4 + 2][r] = v.z; At[c4 * 4 + 3][r] = v.w;
    }
    int kleft = Kdim - k0;
    if (kleft >= BK) {
      for (int t = tid; t < BK * COUT / 4; t += NT)
        ((float4*)&Wl[0][0])[t] = ((const float4*)&W[(size_t)k0 * COUT])[t];
    } else {
      for (int t = tid; t < BK * COUT; t += NT) {
        int kk = t / COUT, o = t % COUT;
        Wl[kk][o] = (kk < kleft) ? W[(size_t)(k0 + kk) * COUT + o] : 0.0f;
      }
    }
    __syncthreads();
#pragma unroll
    for (int kk = 0; kk < BK; kk++) {
      float4 a = *(const float4*)&At[kk][tr * 4];
      float4 w = *(const float4*)&Wl[kk][tc * 4];
      float av[4] = {a.x, a.y, a.z, a.w};
      float wv[4] = {w.x, w.y, w.z, w.w};
#pragma unroll
      for (int i = 0; i < 4; i++)
#pragma unroll
        for (int j = 0; j < 4; j++)
          ar[i][j] = fmaf(av[i], wv[j], ar[i][j]);
    }
    __syncthreads();
  }
  float* gp = gpart + ((size_t)blockIdx.y * M) * COUT + tc * 4;
#pragma unroll
  for (int i = 0; i < 4; i++) {
    int m = m0 + tr * 4 + i;
    if (m < M)
      *(float4*)(gp + (size_t)m * COUT) =
          make_float4(ar[i][0], ar[i][1], ar[i][2], ar[i][3]);
  }
}

// ---------------- epilogue: h = elu(sum_c gpart[c]/max(deg,1) + x@R + b); deg = hist ----------------
__global__ __launch_bounds__(256) void epilogue_kernel(
    const float* __restrict__ gpart, const int* __restrict__ degI,
    const float* __restrict__ x, const float* __restrict__ R,
    const float* __restrict__ b, float* __restrict__ h,
    int N, int Cin, int coutShift, int kchunks) {
  int tid = blockIdx.x * 256 + threadIdx.x;
  int Cout = 1 << coutShift;
  if (tid >= (N << coutShift)) return;
  int n = tid >> coutShift;
  int o = tid & (Cout - 1);
  size_t stride = (size_t)N << coutShift;
  float s = 0.0f;
  for (int c = 0; c < kchunks; c++) s += gpart[(size_t)c * stride + tid];
  s /= (float)max(degI[n], 1);
  float r = b[o];
  const float* xr = &x[n * Cin];
  for (int i = 0; i < Cin; i++) r = fmaf(xr[i], R[i * Cout + o], r);
  float v = s + r;
  h[tid] = v > 0.0f ? v : expm1f(v);
}

// ---------------- pool v5b: named-float4 accumulators, h tile in LDS ----------------
#define FMA4(c, pj, h) \
  c.x = fmaf(pj, h.x, c.x); c.y = fmaf(pj, h.y, c.y); \
  c.z = fmaf(pj, h.z, c.z); c.w = fmaf(pj, h.w, c.w);

template <int COUT, int OPT>
__global__ __launch_bounds__(256) void pool5b_kernel(
    const float* __restrict__ P, const float* __restrict__ h,
    float* __restrict__ partial, int Nsrc, int Nnext, int chunk, int items) {
  extern __shared__ float hs[];
  int c = blockIdx.y;
  int n0 = c * chunk;
  int n1 = min(Nsrc, n0 + chunk);
  int len = n1 - n0;
  for (int t = threadIdx.x; t < len * (COUT / 4); t += 256)
    ((float4*)hs)[t] = ((const float4*)&h[(size_t)n0 * COUT])[t];
  __syncthreads();
  int item = blockIdx.x * 256 + threadIdx.x;
  if (item >= items) return;
  int nj4 = Nnext >> 2;
  int j0 = (item % nj4) << 2;
  int o0 = (item / nj4) * OPT;
  const float4 z = make_float4(0.0f, 0.0f, 0.0f, 0.0f);
  float4 c00 = z, c01 = z, c02 = z, c03 = z;
  float4 c10 = z, c11 = z, c12 = z, c13 = z;
  float4 c20 = z, c21 = z, c22 = z, c23 = z;
  float4 c30 = z, c31 = z, c32 = z, c33 = z;
  const float* Pb = P + j0;

#define USTEP(pv, nn)                                                    \
  {                                                                      \
    const float4* hr = (const float4*)&hs[(nn) * COUT + o0];             \
    float4 h0 = hr[0], h1 = hr[1];                                       \
    FMA4(c00, pv.x, h0) FMA4(c01, pv.x, h1)                              \
    FMA4(c10, pv.y, h0) FMA4(c11, pv.y, h1)                              \
    FMA4(c20, pv.z, h0) FMA4(c21, pv.z, h1)                              \
    FMA4(c30, pv.w, h0) FMA4(c31, pv.w, h1)                              \
    if constexpr (OPT == 16) {                                           \
      float4 h2 = hr[2], h3 = hr[3];                                     \
      FMA4(c02, pv.x, h2) FMA4(c03, pv.x, h3)                            \
      FMA4(c12, pv.y, h2) FMA4(c13, pv.y, h3)                            \
      FMA4(c22, pv.z, h2) FMA4(c23, pv.z, h3)                            \
      FMA4(c32, pv.w, h2) FMA4(c33, pv.w, h3)                            \
    }                                                                    \
  }

  int n = 0;
  for (; n + 4 <= len; n += 4) {
    float4 pv0 = *(const float4*)&Pb[(size_t)(n0 + n + 0) * Nnext];
    float4 pv1 = *(const float4*)&Pb[(size_t)(n0 + n + 1) * Nnext];
    float4 pv2 = *(const float4*)&Pb[(size_t)(n0 + n + 2) * Nnext];
    float4 pv3 = *(const float4*)&Pb[(size_t)(n0 + n + 3) * Nnext];
    USTEP(pv0, n + 0)
    USTEP(pv1, n + 1)
    USTEP(pv2, n + 2)
    USTEP(pv3, n + 3)
  }
  for (; n < len; n++) {
    float4 pv = *(const float4*)&Pb[(size_t)(n0 + n) * Nnext];
    USTEP(pv, n)
  }
#undef USTEP

  float* pp = partial + ((size_t)c * Nnext + j0) * COUT + o0;
  *(float4*)(pp + 0 * COUT + 0) = c00;
  *(float4*)(pp + 0 * COUT + 4) = c01;
  *(float4*)(pp + 1 * COUT + 0) = c10;
  *(float4*)(pp + 1 * COUT + 4) = c11;
  *(float4*)(pp + 2 * COUT + 0) = c20;
  *(float4*)(pp + 2 * COUT + 4) = c21;
  *(float4*)(pp + 3 * COUT + 0) = c30;
  *(float4*)(pp + 3 * COUT + 4) = c31;
  if constexpr (OPT == 16) {
    *(float4*)(pp + 0 * COUT + 8)  = c02;
    *(float4*)(pp + 0 * COUT + 12) = c03;
    *(float4*)(pp + 1 * COUT + 8)  = c12;
    *(float4*)(pp + 1 * COUT + 12) = c13;
    *(float4*)(pp + 2 * COUT + 8)  = c22;
    *(float4*)(pp + 2 * COUT + 12) = c23;
    *(float4*)(pp + 3 * COUT + 8)  = c32;
    *(float4*)(pp + 3 * COUT + 12) = c33;
  }
}

// ---------------- pool reduce ----------------
__global__ __launch_bounds__(256) void preduce_kernel(
    const float* __restrict__ partial, float* __restrict__ xnext,
    int NnCout, int chunks) {
  int i = blockIdx.x * 256 + threadIdx.x;
  if (i >= NnCout) return;
  float s = 0.0f;
  for (int c = 0; c < chunks; c++) s += partial[(size_t)c * NnCout + i];
  xnext[i] = s;
}

// ---------------- final max over 16 nodes -> out[128] ----------------
__global__ __launch_bounds__(128) void max_kernel(const float* __restrict__ x6,
                                                  float* __restrict__ out) {
  int o = threadIdx.x;
  float m = -3.0e38f;
  for (int n = 0; n < 16; n++) m = fmaxf(m, x6[n * 128 + o]);
  out[o] = m;
}

extern "C" void kernel_launch(void* const* d_in, const int* in_sizes, int n_in,
                              void* d_out, int out_size, void* d_ws, size_t ws_size,
                              hipStream_t stream) {
  static const int NSh[7] = {20000, 5000, 1280, 320, 80, 32, 16};
  static const int ESh[6] = {320000, 80000, 20480, 5120, 1280, 512};
  static const int NFh[7] = {2, 16, 32, 64, 128, 128, 128};
  static const int cinSh[6]  = {1, 4, 5, 6, 7, 7};
  static const int coutSh[6] = {4, 5, 6, 7, 7, 7};
  static const int KSt[6] = {256, 2016, 4000, 8000, 16000, 16000};
  static const int kchunksTab[6] = {4, 8, 16, 32, 64, 128};
  static const int ktilesTab[6]  = {2, 8, 8, 8, 8, 4};
  static const int poolChunksTab[6] = {120, 64, 16, 8, 4, 2};
  static const int histOff[6] = {0, 20000, 25000, 26280, 26600, 26680};
  static const int startOff[6] = {0, 20001, 25002, 26283, 26604, 26685};
  static const int Eoff[6] = {0, 320000, 400000, 420480, 425600, 426880};

  const float* x0 = (const float*)d_in[0];
  const int* ei[6];
  const float* ea[6];
  for (int l = 0; l < 6; l++) {
    ei[l] = (const int*)d_in[1 + 2 * l];
    ea[l] = (const float*)d_in[2 + 2 * l];
  }
  const float* Pm[6];
  for (int l = 0; l < 6; l++) Pm[l] = (const float*)d_in[13 + l];
  const float* Wt[6];
  const float* Rt[6];
  const float* bt[6];
  for (int l = 0; l < 6; l++) {
    Wt[l] = (const float*)d_in[19 + 3 * l];
    Rt[l] = (const float*)d_in[20 + 3 * l];
    bt[l] = (const float*)d_in[21 + 3 * l];
  }

  // workspace layout
  float* ws = (float*)d_ws;
  float* A     = ws;                     // max N*KS = 10.08M floats
  float* gpart = ws + 10150000;          // max 1.31M
  float* hbuf  = ws + 11500000;          // 320000
  float* ppart = ws + 11900000;          // max 9.6M
  float* xA    = ws + 21600000;
  float* xB    = ws + 21700000;
  int* hist    = (int*)(ws + 21800000);  // 26712
  int* startA  = (int*)(ws + 21830000);  // 26718
  int* cursor  = (int*)(ws + 21860000);  // 26712
  int* srcS    = (int*)(ws + 21890000);  // 427392
  int* kpkS    = (int*)(ws + 22320000);  // 427392
  float* frS   = ws + 22750000;          // 1282176

  // per-call edge sort (CSR by dst)
  hipMemsetAsync(hist, 0, 26712 * sizeof(int), stream);
  for (int l = 0; l < 6; l++)
    hist_kernel<<<(ESh[l] + 255) / 256, 256, 0, stream>>>(ei[l], hist + histOff[l], ESh[l]);
  scan6_kernel<<<6, 1024, 0, stream>>>(hist, startA, cursor);
  for (int l = 0; l < 6; l++)
    reorder_kernel<<<(ESh[l] + 255) / 256, 256, 0, stream>>>(
        ei[l], ea[l], cursor + histOff[l], srcS + Eoff[l], kpkS + Eoff[l],
        frS + 3 * (size_t)Eoff[l], ESh[l]);

  const float* cur = x0;
  for (int l = 0; l < 6; l++) {
    int N = NSh[l], Nn = NSh[l + 1], Cin = NFh[l], Cout = NFh[l + 1];
    int Kdim = NKER * Cin, KS = KSt[l];
    float* xnext = (l & 1) ? xB : xA;
    const int* st = startA + startOff[l];
    const int* ss = srcS + Eoff[l];
    const int* kk = kpkS + Eoff[l];
    const float* ff = frS + 3 * (size_t)Eoff[l];

    // build A (atomics-free owner-computes; writes pad -> no memset needed)
    switch (l) {
      case 0: build2_l0_kernel<<<313, 64, 0, stream>>>(st, ss, kk, ff, cur, A, N); break;
      case 1: build2_kernel<4, 8, 2000, 2016, 128><<<625, 128, 0, stream>>>(st, ss, kk, ff, cur, A); break;
      case 2: build2_kernel<5, 4, 4000, 4000, 128><<<320, 128, 0, stream>>>(st, ss, kk, ff, cur, A); break;
      case 3: build2_kernel<6, 2, 8000, 8000, 128><<<160, 128, 0, stream>>>(st, ss, kk, ff, cur, A); break;
      case 4: build2_kernel<7, 1, 16000, 16000, 128><<<80, 128, 0, stream>>>(st, ss, kk, ff, cur, A); break;
      default: build2_kernel<7, 1, 16000, 16000, 128><<<32, 128, 0, stream>>>(st, ss, kk, ff, cur, A); break;
    }

    int kchunks = kchunksTab[l], ktiles = ktilesTab[l];
    switch (l) {
      case 0: {
        dim3 g((N + 127) / 128, kchunks);
        gemm3_kernel<128, 16, 128><<<g, 128, 0, stream>>>(A, Wt[l], gpart, N, Kdim, KS, ktiles);
        break;
      }
      case 1: {
        dim3 g((N + 127) / 128, kchunks);
        gemm3_kernel<128, 32, 256><<<g, 256, 0, stream>>>(A, Wt[l], gpart, N, Kdim, KS, ktiles);
        break;
      }
      case 2: {
        dim3 g((N + 63) / 64, kchunks);
        gemm3_kernel<64, 64, 256><<<g, 256, 0, stream>>>(A, Wt[l], gpart, N, Kdim, KS, ktiles);
        break;
      }
      default: {
        dim3 g((N + 31) / 32, kchunks);
        gemm3_kernel<32, 128, 256><<<g, 256, 0, stream>>>(A, Wt[l], gpart, N, Kdim, KS, ktiles);
        break;
      }
    }

    int ethreads = N << coutSh[l];
    epilogue_kernel<<<(ethreads + 255) / 256, 256, 0, stream>>>(
        gpart, hist + histOff[l], cur, Rt[l], bt[l], hbuf, N, Cin, coutSh[l], kchunks);

    int pc = poolChunksTab[l];
    int chunk = (N + pc - 1) / pc;
    size_t ldsB = (size_t)chunk * Cout * sizeof(float);
    int items, gx;
    switch (Cout) {
      case 16:
        items = (Nn >> 2) * 1;
        gx = (items + 255) / 256;
        pool5b_kernel<16, 16><<<dim3(gx, pc), 256, ldsB, stream>>>(Pm[l], hbuf, ppart, N, Nn, chunk, items);
        break;
      case 32:
        items = (Nn >> 2) * 2;
        gx = (items + 255) / 256;
        pool5b_kernel<32, 16><<<dim3(gx, pc), 256, ldsB, stream>>>(Pm[l], hbuf, ppart, N, Nn, chunk, items);
        break;
      case 64:
        items = (Nn >> 2) * 8;
        gx = (items + 255) / 256;
        pool5b_kernel<64, 8><<<dim3(gx, pc), 256, ldsB, stream>>>(Pm[l], hbuf, ppart, N, Nn, chunk, items);
        break;
      default:
        items = (Nn >> 2) * 16;
        gx = (items + 255) / 256;
        pool5b_kernel<128, 8><<<dim3(gx, pc), 256, ldsB, stream>>>(Pm[l], hbuf, ppart, N, Nn, chunk, items);
        break;
    }
    int NnCout = Nn << coutSh[l];
    preduce_kernel<<<(NnCout + 255) / 256, 256, 0, stream>>>(ppart, xnext, NnCout, pc);

    cur = xnext;
  }

  max_kernel<<<1, 128, 0, stream>>>(cur, (float*)d_out);
}